// Round 1
// baseline (193.131 us; speedup 1.0000x reference)
//
#include <hip/hip_runtime.h>
#include <math.h>

// Problem constants (match reference)
constexpr int D_ = 64;
constexpr int N_ = 8192;
constexpr int DIM_ = 256;
constexpr int K_ = 32;
constexpr int L_ = 1;
constexpr int P_ = D_ - L_;  // 63
constexpr float TEMP_ = 0.1f;
constexpr float EPS_ = 1e-8f;

constexpr int ROWS_PER_BLOCK = 256;
constexpr int CHUNKS = N_ / ROWS_PER_BLOCK;  // 32

// Kernel 1: streaming pass. Per (d, chunk-of-256-rows) block:
//  - accumulate per-dim sums into sum_all[d][dim] (atomicAdd combine)
//  - write per-row squared L2 norm into normsq[d][n]
// Each wave handles 64 consecutive rows; lane l loads float4 at dim 4l.
__global__ __launch_bounds__(256) void k1_sums_norms(const float* __restrict__ emb,
                                                     float* __restrict__ normsq,
                                                     float* __restrict__ sum_all) {
  const int b = blockIdx.x;
  const int d = b / CHUNKS;
  const int chunk = b % CHUNKS;
  const int tid = threadIdx.x;
  const int wave = tid >> 6;
  const int lane = tid & 63;
  const int row0 = chunk * ROWS_PER_BLOCK + wave * 64;
  const float* base = emb + (size_t)d * N_ * DIM_;

  float a0 = 0.f, a1 = 0.f, a2 = 0.f, a3 = 0.f;
#pragma unroll 4
  for (int r = 0; r < 64; ++r) {
    const int n = row0 + r;
    const float4 v = *reinterpret_cast<const float4*>(base + (size_t)n * DIM_ + (lane << 2));
    a0 += v.x; a1 += v.y; a2 += v.z; a3 += v.w;
    float sq = v.x * v.x + v.y * v.y + v.z * v.z + v.w * v.w;
#pragma unroll
    for (int off = 32; off > 0; off >>= 1) sq += __shfl_down(sq, off, 64);
    if (lane == 0) normsq[(size_t)d * N_ + n] = sq;
  }

  __shared__ float part[4][DIM_];
  part[wave][(lane << 2) + 0] = a0;
  part[wave][(lane << 2) + 1] = a1;
  part[wave][(lane << 2) + 2] = a2;
  part[wave][(lane << 2) + 3] = a3;
  __syncthreads();
  const float s = part[0][tid] + part[1][tid] + part[2][tid] + part[3][tid];
  atomicAdd(&sum_all[d * DIM_ + tid], s);
}

// Kernel 2: per-d top-K selection by norm^2 with stable (lowest index first)
// tie-break, matching jnp.argsort(-norms) semantics for ties.
// One block per d; norms held in LDS; 32 iterative arg-max passes.
__global__ __launch_bounds__(256) void k2_topk(const float* __restrict__ normsq,
                                               int* __restrict__ topidx) {
  const int d = blockIdx.x;
  const int tid = threadIdx.x;
  const int lane = tid & 63;
  const int wave = tid >> 6;

  __shared__ float vals[N_];  // 32 KB
  __shared__ unsigned long long wbest[4];

  for (int i = tid; i < N_; i += 256) vals[i] = normsq[(size_t)d * N_ + i];
  __syncthreads();

  for (int k = 0; k < K_; ++k) {
    // key = (float bits of value) << 32 | (N-1-i): larger value wins, then lower index.
    // Valid because norm^2 >= 0 (float bit pattern is order-preserving for non-negatives).
    unsigned long long best = 0ull;
    for (int i = tid; i < N_; i += 256) {
      const unsigned vb = __float_as_uint(vals[i]);
      const unsigned long long key = ((unsigned long long)vb << 32) | (unsigned)(N_ - 1 - i);
      if (key > best) best = key;
    }
#pragma unroll
    for (int off = 32; off > 0; off >>= 1) {
      const unsigned long long o = __shfl_down(best, off, 64);
      if (o > best) best = o;
    }
    if (lane == 0) wbest[wave] = best;
    __syncthreads();
    if (tid == 0) {
      unsigned long long bb = wbest[0];
      for (int w = 1; w < 4; ++w)
        if (wbest[w] > bb) bb = wbest[w];
      const int idx = N_ - 1 - (int)(bb & 0xFFFFFFFFu);
      topidx[d * K_ + k] = idx;
      vals[idx] = 0.0f;  // remove (all real norms^2 >> 0)
    }
    __syncthreads();
  }
}

// Kernel 3: one block per d. Gather top-K rows, form both samples (sum_all and
// sum_neg = sum_all - top_sum), normalize rows, write nS[128][256].
__global__ __launch_bounds__(256) void k3_samples(const float* __restrict__ emb,
                                                  const float* __restrict__ sum_all,
                                                  const int* __restrict__ topidx,
                                                  float* __restrict__ nS) {
  const int d = blockIdx.x;
  const int t = threadIdx.x;  // dim
  const int lane = t & 63;
  const int wave = t >> 6;
  const float* base = emb + (size_t)d * N_ * DIM_;

  float ts = 0.f;
#pragma unroll 4
  for (int k = 0; k < K_; ++k) {
    const int n = topidx[d * K_ + k];
    ts += base[(size_t)n * DIM_ + t];
  }
  const float s1 = sum_all[d * DIM_ + t];
  const float s2 = s1 - ts;

  float q1 = s1 * s1, q2 = s2 * s2;
#pragma unroll
  for (int off = 32; off > 0; off >>= 1) {
    q1 += __shfl_down(q1, off, 64);
    q2 += __shfl_down(q2, off, 64);
  }
  __shared__ float w1[4], w2[4];
  __shared__ float inv1s, inv2s;
  if (lane == 0) { w1[wave] = q1; w2[wave] = q2; }
  __syncthreads();
  if (t == 0) {
    const float n1 = sqrtf(w1[0] + w1[1] + w1[2] + w1[3]);
    const float n2 = sqrtf(w2[0] + w2[1] + w2[2] + w2[3]);
    inv1s = 1.0f / fmaxf(n1, EPS_);
    inv2s = 1.0f / fmaxf(n2, EPS_);
  }
  __syncthreads();
  nS[d * DIM_ + t] = s1 * inv1s;
  nS[(D_ + d) * DIM_ + t] = s2 * inv2s;
}

// Kernel 4: one block (1 wave, 64 threads) per pair p. Computes pos and 32
// negative sims for both i and j, wave-parallel LSE over 33 logits, atomicAdd
// of (nce_i + nce_j)/(2P) into out[0].
__global__ __launch_bounds__(64) void k4_loss(const float* __restrict__ nS,
                                              const int* __restrict__ negidx,
                                              float* __restrict__ out) {
  const int p = blockIdx.x;
  const int lane = threadIdx.x;

  const float4 vi = *reinterpret_cast<const float4*>(nS + p * DIM_ + (lane << 2));
  const float4 vj = *reinterpret_cast<const float4*>(nS + (p + L_) * DIM_ + (lane << 2));

  float dp = vi.x * vj.x + vi.y * vj.y + vi.z * vj.z + vi.w * vj.w;
#pragma unroll
  for (int off = 1; off < 64; off <<= 1) dp += __shfl_xor(dp, off, 64);
  const float pos = dp;

  float negi = 0.f, negj = 0.f;  // lane k (<32) ends up holding neg sim k
  for (int k = 0; k < K_; ++k) {
    const int idx = negidx[p * K_ + k];
    const float4 vn = *reinterpret_cast<const float4*>(nS + idx * DIM_ + (lane << 2));
    float di = vi.x * vn.x + vi.y * vn.y + vi.z * vn.z + vi.w * vn.w;
    float dj = vj.x * vn.x + vj.y * vn.y + vj.z * vn.z + vj.w * vn.w;
#pragma unroll
    for (int off = 1; off < 64; off <<= 1) {
      di += __shfl_xor(di, off, 64);
      dj += __shfl_xor(dj, off, 64);
    }
    if (lane == k) { negi = di; negj = dj; }
  }

  const float invT = 1.0f / TEMP_;
  const float posT = pos * invT;

  float total = 0.f;
#pragma unroll
  for (int side = 0; side < 2; ++side) {
    const float nv = (side == 0) ? negi : negj;
    float li = (lane < K_) ? nv * invT : -INFINITY;
    float m = fmaxf(li, posT);
#pragma unroll
    for (int off = 1; off < 64; off <<= 1) m = fmaxf(m, __shfl_xor(m, off, 64));
    float e = (lane < K_) ? expf(li - m) : ((lane == 63) ? expf(posT - m) : 0.0f);
#pragma unroll
    for (int off = 1; off < 64; off <<= 1) e += __shfl_xor(e, off, 64);
    const float lse = m + logf(e);
    total += lse - posT;  // -(posT - lse)
  }

  if (lane == 0) atomicAdd(out, total / (2.0f * P_));
}

extern "C" void kernel_launch(void* const* d_in, const int* in_sizes, int n_in,
                              void* d_out, int out_size, void* d_ws, size_t ws_size,
                              hipStream_t stream) {
  const float* emb = (const float*)d_in[0];
  const int* negidx = (const int*)d_in[1];
  float* out = (float*)d_out;

  // Workspace layout (floats):
  float* normsq = (float*)d_ws;                 // D*N = 524288
  float* sum_all = normsq + (size_t)D_ * N_;    // D*DIM = 16384
  float* nS = sum_all + D_ * DIM_;              // 2*D*DIM = 32768
  int* topidx = (int*)(nS + 2 * D_ * DIM_);     // D*K = 2048 ints

  // Zero the accumulation targets (ws/out are poisoned, not re-zeroed by harness).
  hipMemsetAsync(sum_all, 0, D_ * DIM_ * sizeof(float), stream);
  hipMemsetAsync(d_out, 0, sizeof(float), stream);

  k1_sums_norms<<<D_ * CHUNKS, 256, 0, stream>>>(emb, normsq, sum_all);
  k2_topk<<<D_, 256, 0, stream>>>(normsq, topidx);
  k3_samples<<<D_, 256, 0, stream>>>(emb, sum_all, topidx, nS);
  k4_loss<<<P_, 64, 0, stream>>>(nS, negidx, out);
}

// Round 2
// 154.204 us; speedup vs baseline: 1.2524x; 1.2524x over previous
//
#include <hip/hip_runtime.h>
#include <math.h>

// Problem constants (match reference)
constexpr int D_ = 64;
constexpr int N_ = 8192;
constexpr int DIM_ = 256;
constexpr int K_ = 32;
constexpr int L_ = 1;
constexpr int P_ = D_ - L_;  // 63
constexpr float TEMP_ = 0.1f;
constexpr float EPS_ = 1e-8f;

constexpr int ROWS_PER_BLOCK = 256;
constexpr int CHUNKS = N_ / ROWS_PER_BLOCK;  // 32
constexpr int BATCH = 16;                    // rows per wave per LDS round
constexpr int LDSTR = 65;                    // stride (words) -> conflict-free

// Kernel 1: streaming pass, no cross-lane ops in the hot loop.
// Per (d, chunk) block: 4 waves x 64 rows. Lane l loads float4 at dim 4l,
// accumulates per-dim sums in registers, writes per-row partial square to LDS.
// Every 16 rows: block-wide transpose-reduce (4 threads/row, 16 adds each)
// produces the row norms^2, stored coalesced.
__global__ __launch_bounds__(256, 4) void k1_sums_norms(const float* __restrict__ emb,
                                                        float* __restrict__ normsq,
                                                        float* __restrict__ sum_all) {
  const int b = blockIdx.x;
  const int d = b / CHUNKS;
  const int chunk = b % CHUNKS;
  const int tid = threadIdx.x;
  const int wave = tid >> 6;
  const int lane = tid & 63;
  const float* base = emb + (size_t)d * N_ * DIM_;

  __shared__ __align__(16) float sq[4][BATCH * LDSTR];  // 16.25 KB

  float a0 = 0.f, a1 = 0.f, a2 = 0.f, a3 = 0.f;
  const int wrow0 = chunk * ROWS_PER_BLOCK + wave * 64;

  for (int batch = 0; batch < 64 / BATCH; ++batch) {
    const int r0 = wrow0 + batch * BATCH;
#pragma unroll
    for (int r = 0; r < BATCH; ++r) {
      const float4 v = *reinterpret_cast<const float4*>(base + (size_t)(r0 + r) * DIM_ + (lane << 2));
      a0 += v.x; a1 += v.y; a2 += v.z; a3 += v.w;
      sq[wave][r * LDSTR + lane] = v.x * v.x + v.y * v.y + v.z * v.z + v.w * v.w;
    }
    __syncthreads();
    {
      // 64 rows in the block this round; 4 threads per row.
      const int rr = tid >> 2;       // block-row 0..63
      const int q = tid & 3;         // quarter
      const int w = rr >> 4;         // which wave's buffer
      const int r = rr & 15;         // row within batch
      const float* p = &sq[w][r * LDSTR + q * 16];
      float s = 0.f;
#pragma unroll
      for (int i = 0; i < 16; ++i) s += p[i];
      s += __shfl_xor(s, 1, 64);
      s += __shfl_xor(s, 2, 64);
      if (q == 0) {
        const int row = chunk * ROWS_PER_BLOCK + w * 64 + batch * BATCH + r;
        normsq[(size_t)d * N_ + row] = s;
      }
    }
    __syncthreads();
  }

  // Per-dim sums: stash each wave's 256 partials in its LDS region, combine.
  reinterpret_cast<float4*>(&sq[wave][0])[lane] = make_float4(a0, a1, a2, a3);
  __syncthreads();
  const float s = sq[0][tid] + sq[1][tid] + sq[2][tid] + sq[3][tid];
  atomicAdd(&sum_all[d * DIM_ + tid], s);
}

// Kernel 2: per-d top-K by norm^2, stable (lowest index) tie-break, matching
// jnp.argsort(-norms). Incremental: each thread caches the max-key of its own
// 32-element chunk; per pass only the winning chunk's owner rescans.
__global__ __launch_bounds__(256) void k2_topk(const float* __restrict__ normsq,
                                               int* __restrict__ topidx) {
  const int d = blockIdx.x;
  const int tid = threadIdx.x;
  const int lane = tid & 63;
  const int wave = tid >> 6;

  __shared__ float vals[N_];  // 32 KB
  __shared__ unsigned long long wbest[4];

  for (int i = tid; i < N_; i += 256) vals[i] = normsq[(size_t)d * N_ + i];
  __syncthreads();

  // key = (float bits)<<32 | (N-1-i): larger value wins, then lower index.
  // Valid: norms^2 >= 0, so float bits are order-preserving.
  const int cbase = tid * 32;
  unsigned long long my = 0ull;
#pragma unroll 8
  for (int r = 0; r < 32; ++r) {
    const int i = cbase + r;
    const unsigned long long key =
        ((unsigned long long)__float_as_uint(vals[i]) << 32) | (unsigned)(N_ - 1 - i);
    if (key > my) my = key;
  }

  for (int k = 0; k < K_; ++k) {
    unsigned long long b = my;
#pragma unroll
    for (int off = 1; off < 64; off <<= 1) {
      const unsigned long long o = __shfl_xor(b, off, 64);
      if (o > b) b = o;
    }
    if (lane == 0) wbest[wave] = b;
    __syncthreads();
    unsigned long long bb = wbest[0];
    for (int w = 1; w < 4; ++w)
      if (wbest[w] > bb) bb = wbest[w];
    const int idx = N_ - 1 - (int)(bb & 0xFFFFFFFFu);
    if (tid == 0) topidx[d * K_ + k] = idx;
    if ((idx >> 5) == tid) {  // owner: remove and rescan own chunk
      vals[idx] = 0.0f;
      my = 0ull;
      for (int r = 0; r < 32; ++r) {
        const int i = cbase + r;
        const unsigned long long key =
            ((unsigned long long)__float_as_uint(vals[i]) << 32) | (unsigned)(N_ - 1 - i);
        if (key > my) my = key;
      }
    }
    __syncthreads();
  }
}

// Kernel 3: one block per d. Gather top-K rows, form both samples, normalize,
// write nS[128][256]. Block 0 also zeroes the loss accumulator (runs before k4).
__global__ __launch_bounds__(256) void k3_samples(const float* __restrict__ emb,
                                                  const float* __restrict__ sum_all,
                                                  const int* __restrict__ topidx,
                                                  float* __restrict__ nS,
                                                  float* __restrict__ out) {
  const int d = blockIdx.x;
  const int t = threadIdx.x;  // dim
  const int lane = t & 63;
  const int wave = t >> 6;
  if (d == 0 && t == 0) out[0] = 0.0f;
  const float* base = emb + (size_t)d * N_ * DIM_;

  float ts = 0.f;
#pragma unroll 4
  for (int k = 0; k < K_; ++k) {
    const int n = topidx[d * K_ + k];
    ts += base[(size_t)n * DIM_ + t];
  }
  const float s1 = sum_all[d * DIM_ + t];
  const float s2 = s1 - ts;

  float q1 = s1 * s1, q2 = s2 * s2;
#pragma unroll
  for (int off = 32; off > 0; off >>= 1) {
    q1 += __shfl_down(q1, off, 64);
    q2 += __shfl_down(q2, off, 64);
  }
  __shared__ float w1[4], w2[4];
  __shared__ float inv1s, inv2s;
  if (lane == 0) { w1[wave] = q1; w2[wave] = q2; }
  __syncthreads();
  if (t == 0) {
    const float n1 = sqrtf(w1[0] + w1[1] + w1[2] + w1[3]);
    const float n2 = sqrtf(w2[0] + w2[1] + w2[2] + w2[3]);
    inv1s = 1.0f / fmaxf(n1, EPS_);
    inv2s = 1.0f / fmaxf(n2, EPS_);
  }
  __syncthreads();
  nS[d * DIM_ + t] = s1 * inv1s;
  nS[(D_ + d) * DIM_ + t] = s2 * inv2s;
}

// Kernel 4: one wave per pair p. pos + 32 neg sims for both i and j,
// wave-parallel LSE over 33 logits, atomicAdd into out[0].
__global__ __launch_bounds__(64) void k4_loss(const float* __restrict__ nS,
                                              const int* __restrict__ negidx,
                                              float* __restrict__ out) {
  const int p = blockIdx.x;
  const int lane = threadIdx.x;

  const float4 vi = *reinterpret_cast<const float4*>(nS + p * DIM_ + (lane << 2));
  const float4 vj = *reinterpret_cast<const float4*>(nS + (p + L_) * DIM_ + (lane << 2));

  float dp = vi.x * vj.x + vi.y * vj.y + vi.z * vj.z + vi.w * vj.w;
#pragma unroll
  for (int off = 1; off < 64; off <<= 1) dp += __shfl_xor(dp, off, 64);
  const float pos = dp;

  float negi = 0.f, negj = 0.f;  // lane k (<32) ends up holding neg sim k
  for (int k = 0; k < K_; ++k) {
    const int idx = negidx[p * K_ + k];
    const float4 vn = *reinterpret_cast<const float4*>(nS + idx * DIM_ + (lane << 2));
    float di = vi.x * vn.x + vi.y * vn.y + vi.z * vn.z + vi.w * vn.w;
    float dj = vj.x * vn.x + vj.y * vn.y + vj.z * vn.z + vj.w * vn.w;
#pragma unroll
    for (int off = 1; off < 64; off <<= 1) {
      di += __shfl_xor(di, off, 64);
      dj += __shfl_xor(dj, off, 64);
    }
    if (lane == k) { negi = di; negj = dj; }
  }

  const float invT = 1.0f / TEMP_;
  const float posT = pos * invT;

  float total = 0.f;
#pragma unroll
  for (int side = 0; side < 2; ++side) {
    const float nv = (side == 0) ? negi : negj;
    float li = (lane < K_) ? nv * invT : -INFINITY;
    float m = fmaxf(li, posT);
#pragma unroll
    for (int off = 1; off < 64; off <<= 1) m = fmaxf(m, __shfl_xor(m, off, 64));
    float e = (lane < K_) ? expf(li - m) : ((lane == 63) ? expf(posT - m) : 0.0f);
#pragma unroll
    for (int off = 1; off < 64; off <<= 1) e += __shfl_xor(e, off, 64);
    const float lse = m + logf(e);
    total += lse - posT;  // -(posT - lse)
  }

  if (lane == 0) atomicAdd(out, total / (2.0f * P_));
}

extern "C" void kernel_launch(void* const* d_in, const int* in_sizes, int n_in,
                              void* d_out, int out_size, void* d_ws, size_t ws_size,
                              hipStream_t stream) {
  const float* emb = (const float*)d_in[0];
  const int* negidx = (const int*)d_in[1];
  float* out = (float*)d_out;

  // Workspace layout (floats):
  float* normsq = (float*)d_ws;                 // D*N = 524288
  float* sum_all = normsq + (size_t)D_ * N_;    // D*DIM = 16384
  float* nS = sum_all + D_ * DIM_;              // 2*D*DIM = 32768
  int* topidx = (int*)(nS + 2 * D_ * DIM_);     // D*K = 2048 ints

  hipMemsetAsync(sum_all, 0, D_ * DIM_ * sizeof(float), stream);

  k1_sums_norms<<<D_ * CHUNKS, 256, 0, stream>>>(emb, normsq, sum_all);
  k2_topk<<<D_, 256, 0, stream>>>(normsq, topidx);
  k3_samples<<<D_, 256, 0, stream>>>(emb, sum_all, topidx, nS, out);
  k4_loss<<<P_, 64, 0, stream>>>(nS, negidx, out);
}